// Round 1
// baseline (809.710 us; speedup 1.0000x reference)
//
#include <hip/hip_runtime.h>
#include <hip/hip_bf16.h>
#include <math.h>

// CnnLstmCrf on MI355X, fp32-exact. Round 3: LSTM restructure —
//  - thread pairing: lane 2j owns gates (i_j,g_j), lane 2j+1 owns (f_j,o_j)
//    (same per-gate summation order as round-2 kernel => bit-identical h/c)
//  - gates handed to the nonlin lane via __shfl_xor, no g_sh round trip
//  - double-buffered h in LDS => ONE barrier per step, implemented as raw
//    s_waitcnt lgkmcnt(0) + s_barrier so vmcnt is NEVER drained: the depth-2
//    global prefetch of pre[] stays in flight across barriers (the old
//    __syncthreads drained vmcnt(0) every step => ~900cy HBM stall per step)
//  - masked steps (p >= len, block-uniform) skip gates/nonlin/barrier
// Sizes: B=64 S=250 CL=16 CV=100 CD=300 CH=50 WD=300 FD=5
// IN=355 H=100 4H=400 HD=200 T=22 START=20 STOP=21
//
// Workspace layout (floats). lstm_out/feats alias the wrep region (dead after gemm).
#define WS_U        0          // 15000 -> pad 15360
#define WS_WPAD     15360      // 896*384 = 344064
#define WS_WREP     359424     // 16000*384 = 6144000 (reused below)
#define WS_PRE      6503424    // 16000*800 = 12800000 (end 19303424 floats = 77.2MB)
#define WS_LSTM     359424     // alias wrep: 16000*200 = 3200000 (< 6144000)
#define WS_FEATS    3559424    // alias wrep tail: 16000*22 = 352000 (ends 3911424)

// ---------------- prep: pad w_ih into [896][384] ----------------
__global__ __launch_bounds__(256) void prepw_kernel(
    const float* __restrict__ wf, const float* __restrict__ wb,
    float* __restrict__ w_pad) {
  int idx = blockIdx.x * 256 + threadIdx.x;
  if (idx >= 896 * 384) return;
  int col = idx % 384, row = idx / 384;
  float v = 0.f;
  if (col < 355) {
    if (row < 400)      v = wf[row * 355 + col];
    else if (row < 800) v = wb[(row - 400) * 355 + col];
  }
  w_pad[idx] = v;
}

// ---------------- U table: U[(c*3+k)*50+o] ----------------
__global__ __launch_bounds__(256) void u_kernel(
    const float* __restrict__ char_emb, const float* __restrict__ conv_w,
    float* __restrict__ U) {
  int idx = blockIdx.x * 256 + threadIdx.x;
  if (idx >= 15000) return;
  int c = idx / 150, rem = idx % 150, k = rem / 50, o = rem % 50;
  float acc = 0.f;
  for (int i = 0; i < 300; i++)
    acc += char_emb[c * 300 + i] * conv_w[(o * 300 + i) * 3 + k];
  U[idx] = acc;
}

// ---------------- assemble word_rep rows ----------------
__global__ __launch_bounds__(64) void assemble_kernel(
    const int* __restrict__ batch_word, const int* __restrict__ batch_feats,
    const int* __restrict__ batch_char, const int* __restrict__ recover,
    const float* __restrict__ word_emb, const float* __restrict__ feat_emb,
    const float* __restrict__ conv_b, const float* __restrict__ U,
    float* __restrict__ wrep) {
  int n = blockIdx.x;
  int tid = threadIdx.x;
  __shared__ int ch[16];
  if (tid < 16) ch[tid] = batch_char[(size_t)recover[n] * 16 + tid];
  __syncthreads();
  float* dst = wrep + (size_t)n * 384;
  int w = batch_word[n];
  for (int i = tid; i < 300; i += 64) dst[i] = word_emb[(size_t)w * 300 + i];
  if (tid < 34) {  // feat_emb (5) + zero pad (29)
    int i = 350 + tid;
    dst[i] = (i < 355) ? feat_emb[batch_feats[n] * 5 + (i - 350)] : 0.f;
  }
  if (tid < 50) {  // char CNN via U table, max over 16 positions
    int o = tid;
    float bo = conv_b[o];
    float m = -1e30f;
#pragma unroll
    for (int l = 0; l < 16; l++) {
      float v = bo + U[(ch[l] * 3 + 1) * 50 + o];
      if (l > 0)  v += U[(ch[l - 1] * 3 + 0) * 50 + o];
      if (l < 15) v += U[(ch[l + 1] * 3 + 2) * 50 + o];
      m = fmaxf(m, v);
    }
    dst[300 + o] = m;
  }
}

// ---------------- fp32 GEMM: C[16000][800] = A[16000][384] @ B[896][384]^T + bias
__global__ __launch_bounds__(256, 4) void gemm_kernel(
    const float* __restrict__ A, const float* __restrict__ B,
    float* __restrict__ C, const float* __restrict__ bf,
    const float* __restrict__ bb) {
  __shared__ float As[16][128];
  __shared__ float Bs[16][128];
  int tid = threadIdx.x;
  int m0 = blockIdx.x * 128;
  int n0 = blockIdx.y * 128;
  int tx = tid & 15, ty = tid >> 4;
  int lr = tid >> 2;
  int lc = (tid & 3) * 4;
  float acc[8][8];
#pragma unroll
  for (int i = 0; i < 8; i++)
#pragma unroll
    for (int j = 0; j < 8; j++) acc[i][j] = 0.f;

  for (int k0 = 0; k0 < 384; k0 += 16) {
#pragma unroll
    for (int h = 0; h < 2; h++) {
      int row = lr + h * 64;
      float4 av = *(const float4*)(A + (size_t)(m0 + row) * 384 + k0 + lc);
      As[lc + 0][row] = av.x; As[lc + 1][row] = av.y;
      As[lc + 2][row] = av.z; As[lc + 3][row] = av.w;
      float4 bv = *(const float4*)(B + (size_t)(n0 + row) * 384 + k0 + lc);
      Bs[lc + 0][row] = bv.x; Bs[lc + 1][row] = bv.y;
      Bs[lc + 2][row] = bv.z; Bs[lc + 3][row] = bv.w;
    }
    __syncthreads();
#pragma unroll
    for (int k = 0; k < 16; k++) {
      float a[8], b[8];
      *(float4*)&a[0] = *(const float4*)&As[k][ty * 8];
      *(float4*)&a[4] = *(const float4*)&As[k][ty * 8 + 4];
      *(float4*)&b[0] = *(const float4*)&Bs[k][tx * 8];
      *(float4*)&b[4] = *(const float4*)&Bs[k][tx * 8 + 4];
#pragma unroll
      for (int i = 0; i < 8; i++)
#pragma unroll
        for (int j = 0; j < 8; j++) acc[i][j] += a[i] * b[j];
    }
    __syncthreads();
  }
#pragma unroll
  for (int i = 0; i < 8; i++) {
    int m = m0 + ty * 8 + i;
#pragma unroll
    for (int jj = 0; jj < 8; jj++) {
      int j = n0 + tx * 8 + jj;
      if (j < 800) {
        float bias = (j < 400) ? bf[j] : bb[j - 400];
        C[(size_t)m * 800 + j] = acc[i][jj] + bias;
      }
    }
  }
}

// ---------------- BiLSTM scan: 128 blocks = (dir, row) ----------------
// Lane pairing: even lane t=2j computes gates (i_j, g_j) = Wh rows (j, 200+j);
// odd lane t=2j+1 computes (f_j, o_j) = rows (100+j, 300+j). This matches the
// round-2 kernel's per-thread gate grouping exactly, so every dot product is
// accumulated in the identical order => bit-identical gate values. The odd
// lane receives (i,g) via shuffle and runs the verbatim nonlin expressions.
__global__ __launch_bounds__(256, 1) void lstm_kernel(
    const float* __restrict__ pre, const float* __restrict__ w_hh_f,
    const float* __restrict__ w_hh_b, const int* __restrict__ wordlen,
    float* __restrict__ lstm_out) {
  int t = threadIdx.x;
  int dir = blockIdx.x >> 6;
  int r = blockIdx.x & 63;
  int len = wordlen[r];
  const float* __restrict__ Wh = dir ? w_hh_b : w_hh_f;
  __shared__ __align__(16) float h0[112];
  __shared__ __align__(16) float h1[112];

  const int j = t >> 1;
  const int odd = t & 1;
  const int rA = odd * 100 + j;       // gate row for g1
  const int rB = rA + 200;            // gate row for g2
  float4 WA[25], WB[25];
  if (t < 200) {
    const float4* wa = (const float4*)(Wh + (size_t)rA * 100);
    const float4* wb = (const float4*)(Wh + (size_t)rB * 100);
#pragma unroll
    for (int q = 0; q < 25; q++) { WA[q] = wa[q]; WB[q] = wb[q]; }
  }
  if (t < 112) { h0[t] = 0.f; h1[t] = 0.f; }

  float c_reg = 0.f, h_reg = 0.f;
  const float* __restrict__ pr = pre + dir * 400;
  const int p0 = dir ? 249 : 0;
  const int dp = dir ? -1 : 1;
  const size_t rowbase = (size_t)r * 250;
  const int j1 = rA;                  // pre column for g1
  const int j2 = rB;                  // pre column for g2

  // depth-2 prefetch of pre rows (step 0 and step 1)
  float pvA1 = 0.f, pvA2 = 0.f, pvB1 = 0.f, pvB2 = 0.f;
  if (t < 200) {
    size_t offA = (rowbase + (size_t)p0) * 800;
    pvA1 = pr[offA + j1]; pvA2 = pr[offA + j2];
    size_t offB = (rowbase + (size_t)(p0 + dp)) * 800;
    pvB1 = pr[offB + j1]; pvB2 = pr[offB + j2];
  }
  __syncthreads();  // one-time full drain: h buffers + weights ready

#define LSTM_STEP(I, HRD, HWR, V1, V2)                                         \
  do {                                                                         \
    const int p = p0 + dp * (I);                                               \
    const bool valid = (p < len); /* block-uniform branch */                   \
    float g1 = 0.f, g2 = 0.f;                                                  \
    if (valid && t < 200) {                                                    \
      g1 = V1; g2 = V2;                                                        \
      _Pragma("unroll")                                                        \
      for (int q = 0; q < 25; q++) {                                           \
        float4 hv = *(const float4*)&(HRD)[4 * q];                             \
        g1 += hv.x * WA[q].x + hv.y * WA[q].y + hv.z * WA[q].z +               \
              hv.w * WA[q].w;                                                  \
        g2 += hv.x * WB[q].x + hv.y * WB[q].y + hv.z * WB[q].z +               \
              hv.w * WB[q].w;                                                  \
      }                                                                        \
    }                                                                          \
    if (t < 200) { /* keep prefetch pipeline running every step */             \
      const int ip = ((I) + 2 < 250) ? (I) + 2 : (I);                          \
      const size_t offp = (rowbase + (size_t)(p0 + dp * ip)) * 800;            \
      V1 = pr[offp + j1];                                                      \
      V2 = pr[offp + j2];                                                      \
    }                                                                          \
    if (valid) {                                                               \
      const float gi_in = __shfl_xor(g1, 1, 64); /* odd gets even's i-gate */  \
      const float gg_in = __shfl_xor(g2, 1, 64); /* odd gets even's g-gate */  \
      if (t < 200 && odd) {                                                    \
        const float si = 1.f / (1.f + expf(-gi_in));                           \
        const float sf = 1.f / (1.f + expf(-g1));                              \
        const float so = 1.f / (1.f + expf(-g2));                              \
        c_reg = sf * c_reg + si * tanhf(gg_in);                                \
        h_reg = so * tanhf(c_reg);                                             \
        (HWR)[j] = h_reg;                                                      \
        lstm_out[(rowbase + (size_t)p) * 200 + dir * 100 + j] = h_reg;         \
      }                                                                        \
      /* LDS-only drain + rendezvous; vmcnt stays outstanding (prefetch!) */   \
      asm volatile("s_waitcnt lgkmcnt(0)" ::: "memory");                       \
      __builtin_amdgcn_s_barrier();                                           \
    } else if (t < 200 && odd) {                                               \
      /* masked step: carry h, no LDS traffic, no barrier needed */            \
      lstm_out[(rowbase + (size_t)p) * 200 + dir * 100 + j] = h_reg;           \
    }                                                                          \
  } while (0)

#pragma unroll 1
  for (int ii = 0; ii < 250; ii += 2) {
    LSTM_STEP(ii,     h0, h1, pvA1, pvA2);
    LSTM_STEP(ii + 1, h1, h0, pvB1, pvB2);
  }
#undef LSTM_STEP
}

// ---------------- projection: feats = lstm_out @ proj_w + proj_b ----------------
__global__ __launch_bounds__(256) void proj_kernel(
    const float* __restrict__ lstm_out, const float* __restrict__ proj_w,
    const float* __restrict__ proj_b, float* __restrict__ feats) {
  __shared__ float L[8][200];
  int tid = threadIdx.x;
  size_t base = (size_t)blockIdx.x * 8 * 200;
  for (int idx = tid; idx < 1600; idx += 256)
    L[idx / 200][idx % 200] = lstm_out[base + idx];
  __syncthreads();
  int ty = tid >> 5, c = tid & 31;
  if (c < 22) {
    float acc = proj_b[c];
#pragma unroll 8
    for (int k = 0; k < 200; k++) acc += L[ty][k] * proj_w[k * 22 + c];
    feats[((size_t)blockIdx.x * 8 + ty) * 22 + c] = acc;
  }
}

// ---------------- Viterbi: one wave per batch row (BORING: LDS delta) ----------
__global__ __launch_bounds__(64) void viterbi_kernel(
    const float* __restrict__ feats, const float* __restrict__ trans,
    const int* __restrict__ wordlen, int* __restrict__ out) {
  int r = blockIdx.x;
  int lane = threadIdx.x;
  __shared__ float dsh[22];          // delta (current)
  __shared__ float tsh[22][23];      // trans[k][c], padded stride 23
  __shared__ unsigned char bps[250][22];
  int len = wordlen[r];
  const float* __restrict__ fr = feats + (size_t)r * 250 * 22;
  for (int idx = lane; idx < 484; idx += 64)
    tsh[idx / 22][idx % 22] = trans[idx];
  if (lane < 22) dsh[lane] = trans[20 * 22 + lane] + fr[lane];  // START row
  __syncthreads();
  for (int t = 1; t < 250; t++) {
    float best = -1e30f, fv = 0.f;
    int arg = 0;
    if (lane < 22) {
      fv = fr[t * 22 + lane];
#pragma unroll
      for (int k = 0; k < 22; k++) {
        float cand = dsh[k] + tsh[k][lane];
        if (cand > best) { best = cand; arg = k; }  // first-max == np.argmax
      }
    }
    __syncthreads();  // all dsh reads complete
    if (lane < 22) {
      bool valid = t < len;
      if (valid) dsh[lane] = best + fv;
      bps[t][lane] = valid ? (unsigned char)arg : (unsigned char)lane;
    }
    __syncthreads();  // dsh writes visible
  }
  if (lane == 0) {
    float best = -1e30f;
    int last = 0;
#pragma unroll
    for (int k = 0; k < 22; k++) {
      float cand = dsh[k] + tsh[k][21];  // + trans[:, STOP]
      if (cand > best) { best = cand; last = k; }
    }
    int tag = last;
    out[r * 250 + 249] = tag;
    for (int t = 249; t >= 1; t--) {
      tag = bps[t][tag];
      out[r * 250 + t - 1] = tag;
    }
  }
}

extern "C" void kernel_launch(void* const* d_in, const int* in_sizes, int n_in,
                              void* d_out, int out_size, void* d_ws, size_t ws_size,
                              hipStream_t stream) {
  const int* batch_word  = (const int*)d_in[0];
  const int* batch_feats = (const int*)d_in[1];
  const int* wordlen     = (const int*)d_in[2];
  const int* batch_char  = (const int*)d_in[3];
  // d_in[4] batch_charlen: unused by reference
  const int* recover     = (const int*)d_in[5];
  // d_in[6] mask: recomputed from wordlen (bool dtype ambiguity)
  const float* char_emb  = (const float*)d_in[7];
  const float* word_emb  = (const float*)d_in[8];
  const float* feat_emb  = (const float*)d_in[9];
  const float* conv_w    = (const float*)d_in[10];
  const float* conv_b    = (const float*)d_in[11];
  const float* w_ih_f    = (const float*)d_in[12];
  const float* w_hh_f    = (const float*)d_in[13];
  const float* b_f       = (const float*)d_in[14];
  const float* w_ih_b    = (const float*)d_in[15];
  const float* w_hh_b    = (const float*)d_in[16];
  const float* b_b       = (const float*)d_in[17];
  const float* proj_w    = (const float*)d_in[18];
  const float* proj_b    = (const float*)d_in[19];
  const float* trans     = (const float*)d_in[20];
  int* out = (int*)d_out;
  float* ws = (float*)d_ws;

  float* U        = ws + WS_U;
  float* w_pad    = ws + WS_WPAD;
  float* wrep     = ws + WS_WREP;
  float* pre      = ws + WS_PRE;
  float* lstm_out = ws + WS_LSTM;   // aliases wrep (dead after gemm)
  float* feats    = ws + WS_FEATS;  // aliases wrep tail

  prepw_kernel<<<1344, 256, 0, stream>>>(w_ih_f, w_ih_b, w_pad);
  u_kernel<<<59, 256, 0, stream>>>(char_emb, conv_w, U);
  assemble_kernel<<<16000, 64, 0, stream>>>(batch_word, batch_feats, batch_char,
                                            recover, word_emb, feat_emb, conv_b,
                                            U, wrep);
  dim3 ggrid(125, 7);
  gemm_kernel<<<ggrid, 256, 0, stream>>>(wrep, w_pad, pre, b_f, b_b);
  lstm_kernel<<<128, 256, 0, stream>>>(pre, w_hh_f, w_hh_b, wordlen, lstm_out);
  proj_kernel<<<2000, 256, 0, stream>>>(lstm_out, proj_w, proj_b, feats);
  viterbi_kernel<<<64, 64, 0, stream>>>(feats, trans, wordlen, out);
}